// Round 19
// baseline (210.106 us; speedup 1.0000x reference)
//
#include <hip/hip_runtime.h>
#include <math.h>

typedef unsigned short u16;
typedef __attribute__((ext_vector_type(8))) short bf16x8;
typedef __attribute__((ext_vector_type(4))) float f32x4;

// ---------------- workspace layout (float-element offsets) ----------------
static const size_t WS_FEA1B = 0;          // 8*160*160*64 bf16 NHWC -> 6,553,600 floats
static const size_t WS_FEA2B = 6553600;    // 8*80*80*128 bf16 NHWC -> 3,276,800
static const size_t WS_FEA3B = 9830400;    // 8*40*40*256 bf16 NHWC -> 1,638,400
static const size_t WS_ZLS   = 11468800;   // 12,800
static const size_t WS_FEATT = 11481600;   // K-major feat: 800 jt * 2048 u16 (region reserves 2x)
static const size_t WS_LAB   = 13120000;   // 12,800 int
static const size_t WS_PART  = 13132800;   // 64*50*112 = 358,400
static const size_t WS_ACC   = 13491200;   // 16 floats (acc[7]=maxnorm2 bits, acc[8]=N1)
static const size_t WS_FC    = 13491216;   // 64
static const size_t WS_CSUM  = 13491280;   // 256
static const size_t WS_WT2   = 13491536;   // 36,864
static const size_t WS_WT3   = 13528400;   // 147,456
static const size_t WS_WPT   = 13675856;   // 16,384
// end 13,692,240 floats = 54.8 MB

#define NJS 50   // contrast j-splits; 256 j per block = 16 jt tiles

// featT element (row j, channel c) at u16 index (COMPACT, fully dense):
//   (j>>4)*2048 + ((c>>3)*16 + (j&15))*8 + (c&7)

__device__ inline u16 f2bf(float x) {
    unsigned int u = __float_as_uint(x);
    unsigned int r = u + 0x7fffu + ((u >> 16) & 1u);
    return (u16)(r >> 16);
}
__device__ inline float bf2f(u16 v) {
    return __uint_as_float((unsigned int)v << 16);
}

// ---------------- weight transform + accumulator zeroing ----------------
__global__ __launch_bounds__(256) void wtrans(
    const float* __restrict__ W2, const float* __restrict__ W3,
    const float* __restrict__ Wp,
    u16* __restrict__ wt2, u16* __restrict__ wt3, u16* __restrict__ wpt,
    float* __restrict__ accz)
{
    int tid = blockIdx.x * 256 + threadIdx.x;
    if (blockIdx.x == 0) {
        for (int i = threadIdx.x; i < 336; i += 256)   // acc(16)+fc(64)+csum(256)
            accz[i] = 0.f;
    }
    if (tid < 73728) {               // W2: Co=128, Ci=64
        int ci = tid & 63, rest = tid >> 6;
        int co = rest & 127, tap = rest >> 7;
        wt2[tid] = f2bf(W2[((size_t)co*64 + ci)*9 + tap]);
    } else if (tid < 368640) {       // W3: Co=256, Ci=128
        int t3 = tid - 73728;
        int ci = t3 & 127, rest = t3 >> 7;
        int co = rest & 255, tap = rest >> 8;
        wt3[t3] = f2bf(W3[((size_t)co*128 + ci)*9 + tap]);
    } else {                         // Wp: [128][256]
        int tp = tid - 368640;
        wpt[tp] = f2bf(Wp[tp]);
    }
}

// ---------------- conv1: 3->64, 320->160, NHWC bf16 out ----------------
__global__ __launch_bounds__(256) void conv1_k(
    const float* __restrict__ x_l, const float* __restrict__ x_ul,
    const float* __restrict__ W1, u16* __restrict__ fea1b)
{
    int oy = blockIdx.x;
    int n  = blockIdx.y;
    const float* x = (n < 4) ? x_l + (size_t)n*307200
                             : x_ul + (size_t)(n-4)*307200;
    int t = threadIdx.x;
    int co = t & 63, g = t >> 6;
    __shared__ float lds[9*324];
    for (int u = t; u < 9*322; u += 256) {
        int plane = u / 322, col = u - plane*322;
        int ci = plane / 3, ky = plane - ci*3;
        int iy = oy*2 + ky;
        float v = 0.f;
        if (iy < 320 && col < 320)
            v = x[((size_t)ci*320 + iy)*320 + col];
        lds[plane*324 + col] = v;
    }
    __syncthreads();
    float w[27];
    #pragma unroll
    for (int k = 0; k < 27; ++k) w[k] = W1[co*27 + k];
    float acc[40];
    #pragma unroll
    for (int i = 0; i < 40; ++i) acc[i] = 0.f;
    #pragma unroll
    for (int ci = 0; ci < 3; ++ci) {
        #pragma unroll
        for (int ky = 0; ky < 3; ++ky) {
            const float* base = &lds[(ci*3+ky)*324 + g*80];
            const float* wk = &w[(ci*3+ky)*3];
            #pragma unroll
            for (int q = 0; q < 10; ++q) {
                float4 a = *(const float4*)&base[q*8];
                float4 b = *(const float4*)&base[q*8+4];
                float2 c = *(const float2*)&base[q*8+8];
                float xx[10] = {a.x,a.y,a.z,a.w,b.x,b.y,b.z,b.w,c.x,c.y};
                #pragma unroll
                for (int oo = 0; oo < 4; ++oo)
                    acc[q*4+oo] += wk[0]*xx[2*oo] + wk[1]*xx[2*oo+1] + wk[2]*xx[2*oo+2];
            }
        }
    }
    u16* dst = fea1b + (((size_t)n*160 + oy)*160 + g*40)*64 + co;
    #pragma unroll
    for (int i = 0; i < 40; ++i)
        dst[(size_t)i*64] = f2bf(fmaxf(acc[i], 0.f));
}

// ---------------- implicit-GEMM MFMA conv 3x3 s2 (+ReLU), NHWC in/out ----------------
template<int Ci, int Co, int H, int OH, int COG>
__global__ __launch_bounds__(256) void conv3x3_nhwc(
    const u16* __restrict__ inb, const u16* __restrict__ wt,
    u16* __restrict__ outb)
{
    constexpr int TILES = OH/8;
    int tile = blockIdx.x;
    int co0  = blockIdx.y * (64*COG);
    int n    = blockIdx.z;
    int ty = tile / TILES, tx = tile - ty*TILES;
    int oy0 = ty*8, ox0 = tx*8;
    int iy0 = oy0*2, ix0 = ox0*2;
    int t = threadIdx.x, lane = t & 63, wv = t >> 6;
    int idx15 = lane & 15, kg = lane >> 4;

    __shared__ u16 lds[306*40];   // 24,480 B

    f32x4 acc[COG][4];
    #pragma unroll
    for (int cog = 0; cog < COG; ++cog)
        #pragma unroll
        for (int nt = 0; nt < 4; ++nt) acc[cog][nt] = (f32x4){0.f,0.f,0.f,0.f};

    int goff[5], loff[5];
    #pragma unroll
    for (int i = 0; i < 5; ++i) {
        int u = t + i*256;
        if (u < 1224) {
            int pix = u >> 2, q = u & 3;
            int iyl = pix / 18, j = pix - iyl*18;
            int iy = iy0 + iyl, ix = ix0 + j;
            bool ok = (iy < H && ix < H);
            goff[i] = ok ? (((n*H + iy)*H + ix)*Ci + q*8) : -1;
            int jp = (j & 1)*9 + (j >> 1);
            loff[i] = (iyl*18 + jp)*40 + q*8;
        } else goff[i] = -2;
    }
    uint4 vreg[5];
    #pragma unroll
    for (int i = 0; i < 5; ++i) {
        if (goff[i] == -2) continue;
        vreg[i] = (goff[i] >= 0) ? *(const uint4*)&inb[(size_t)goff[i]]
                                 : make_uint4(0,0,0,0);
    }

    for (int c0 = 0; c0 < Ci; c0 += 32) {
        __syncthreads();
        #pragma unroll
        for (int i = 0; i < 5; ++i)
            if (goff[i] != -2) *(uint4*)&lds[loff[i]] = vreg[i];
        __syncthreads();
        if (c0 + 32 < Ci) {
            #pragma unroll
            for (int i = 0; i < 5; ++i) {
                if (goff[i] == -2) continue;
                vreg[i] = (goff[i] >= 0) ? *(const uint4*)&inb[(size_t)goff[i] + c0 + 32]
                                         : make_uint4(0,0,0,0);
            }
        }

        bf16x8 A[COG][9];
        #pragma unroll
        for (int cog = 0; cog < COG; ++cog) {
            const u16* wb = wt + (size_t)(co0 + cog*64 + wv*16 + idx15)*Ci + c0 + kg*8;
            #pragma unroll
            for (int tap = 0; tap < 9; ++tap)
                A[cog][tap] = *(const bf16x8*)(wb + (size_t)tap*Co*Ci);
        }

        #pragma unroll
        for (int tap = 0; tap < 9; ++tap) {
            int ky = tap/3, kx = tap - ky*3;
            #pragma unroll
            for (int nt = 0; nt < 4; ++nt) {
                int l = nt*16 + idx15;
                int iyl = 2*(l>>3) + ky;
                int j = 2*(l&7) + kx;
                int jp = (j&1)*9 + (j>>1);
                bf16x8 B = *(const bf16x8*)&lds[(size_t)(iyl*18 + jp)*40 + kg*8];
                #pragma unroll
                for (int cog = 0; cog < COG; ++cog)
                    acc[cog][nt] = __builtin_amdgcn_mfma_f32_16x16x32_bf16(A[cog][tap], B, acc[cog][nt], 0, 0, 0);
            }
        }
    }

    #pragma unroll
    for (int cog = 0; cog < COG; ++cog) {
        int co = co0 + cog*64 + wv*16 + kg*4;
        #pragma unroll
        for (int nt = 0; nt < 4; ++nt) {
            int l = nt*16 + idx15;
            int oy = oy0 + (l>>3), ox = ox0 + (l&7);
            u16* dst = outb + (((size_t)n*OH + oy)*OH + ox)*Co + co;
            unsigned int p0 = (unsigned int)f2bf(fmaxf(acc[cog][nt][0],0.f))
                            | ((unsigned int)f2bf(fmaxf(acc[cog][nt][1],0.f)) << 16);
            unsigned int p1 = (unsigned int)f2bf(fmaxf(acc[cog][nt][2],0.f))
                            | ((unsigned int)f2bf(fmaxf(acc[cog][nt][3],0.f)) << 16);
            *(uint2*)dst = make_uint2(p0, p1);
        }
    }
}

// ---------------- fused 1x1 classifier + unlabeled losses + N1 count ----------------
__global__ __launch_bounds__(256) void cls_ul_fused(
    const u16* __restrict__ feab, const float* __restrict__ Wc,
    const float* __restrict__ bc, const float* __restrict__ z_ema,
    float* __restrict__ zls, int* __restrict__ lab_all,
    float* __restrict__ acc, float* __restrict__ fc_cnt)
{
    int gid = blockIdx.x * 256 + threadIdx.x;   // 51200 = 12800 px * 4
    int px = gid >> 2, part = gid & 3;
    int n = px / 1600, r = px - n*1600;
    const u16* f = feab + (size_t)px * 256 + part*64;
    const float* w0 = Wc + part*64;
    const float* w1 = Wc + 256 + part*64;
    float a0 = 0.f, a1 = 0.f;
    #pragma unroll
    for (int ci = 0; ci < 64; ci += 8) {
        bf16x8 v = *(const bf16x8*)&f[ci];
        #pragma unroll
        for (int j = 0; j < 8; ++j) {
            float x = bf2f((u16)v[j]);
            a0 += x * w0[ci+j];
            a1 += x * w1[ci+j];
        }
    }
    a0 += __shfl_xor(a0, 1); a0 += __shfl_xor(a0, 2);
    a1 += __shfl_xor(a1, 1); a1 += __shfl_xor(a1, 2);

    bool ul = (n >= 4);                 // uniform per wave (100 waves per image)
    float ent = 0.f, cn = 0.f, cd = 0.f, pn = 0.f;
    if (part == 0) {
        if (!ul) {
            zls[(size_t)n*3200 + r]        = a0;
            zls[(size_t)n*3200 + 1600 + r] = a1;
        } else {
            int nu = n - 4;
            float z0 = a0 + bc[0], z1 = a1 + bc[1];
            float m = fmaxf(z0, z1);
            float e0 = expf(z0 - m), e1 = expf(z1 - m);
            float lse = m + logf(e0 + e1);
            float lp0 = z0 - lse, lp1 = z1 - lse;
            float p0 = expf(lp0), p1 = expf(lp1);
            ent = -(p0*lp0 + p1*lp1);
            int pl = (z1 > z0) ? 1 : 0;
            float ze0 = z_ema[(size_t)nu*3200 + r], ze1 = z_ema[(size_t)nu*3200 + 1600 + r];
            float me = fmaxf(ze0, ze1);
            float f0 = expf(ze0 - me), f1 = expf(ze1 - me);
            float maxp = 1.f / (f0 + f1);
            int ple = (ze1 > ze0) ? 1 : 0;
            bool mask = (maxp > 0.6f);
            float nll = lse - (ple ? z1 : z0);

            int yy = r / 40, xx = r - yy*40;
            int pi = yy / 10, hi = yy % 10, pj = xx / 10, wi = xx % 10;
            int patch = (pi*4 + pj)*4 + nu;
            int row = patch * 100 + hi*10 + wi;
            lab_all[row]        = pl;
            lab_all[6400 + row] = ple;
            atomicAdd(&fc_cnt[patch], (float)pl);
            cn = mask ? nll : 0.f;
            cd = mask ? 1.f : 0.f;
            pn = (float)(pl + ple);     // N1 contribution (both halves)
        }
    }
    #pragma unroll
    for (int off = 32; off; off >>= 1) {
        ent += __shfl_down(ent, off);
        cn  += __shfl_down(cn, off);
        cd  += __shfl_down(cd, off);
        pn  += __shfl_down(pn, off);
    }
    if ((threadIdx.x & 63) == 0 && ul) {
        atomicAdd(&acc[2], ent);
        atomicAdd(&acc[3], cn);
        atomicAdd(&acc[4], cd);
        atomicAdd(&acc[8], pn);
    }
}

// ---------------- supervised CE: grid-stride + block reduce ----------------
__global__ __launch_bounds__(256) void loss_sup_kernel(
    const float* __restrict__ zs, const int* __restrict__ y,
    const float* __restrict__ bc, float* __restrict__ acc)
{
    const float step = 39.0f / 319.0f;
    float b0 = bc[0], b1 = bc[1];
    float vn = 0.f, vd = 0.f;
    for (int idx = blockIdx.x*256 + threadIdx.x; idx < 409600; idx += gridDim.x*256) {
        int n  = idx / 102400;
        int r  = idx - n*102400;
        int oy = r / 320, ox = r - oy*320;
        float ty = (float)oy * step, tx = (float)ox * step;
        int y0 = (int)ty, x0 = (int)tx;
        int y1 = min(y0 + 1, 39), x1 = min(x0 + 1, 39);
        float wy = ty - (float)y0, wx = tx - (float)x0;
        const float* base = zs + (size_t)n * 3200;
        float z[2];
        #pragma unroll
        for (int c = 0; c < 2; ++c) {
            const float* pl = base + c * 1600;
            float v00 = pl[y0*40 + x0], v01 = pl[y0*40 + x1];
            float v10 = pl[y1*40 + x0], v11 = pl[y1*40 + x1];
            float top = v00 * (1.f - wx) + v01 * wx;
            float bot = v10 * (1.f - wx) + v11 * wx;
            z[c] = top * (1.f - wy) + bot * wy + (c ? b1 : b0);
        }
        int lab = y[idx];
        bool valid = (lab != 255);
        int sl = min(max(lab, 0), 1);
        float mz  = fmaxf(z[0], z[1]);
        float lse = mz + logf(expf(z[0]-mz) + expf(z[1]-mz));
        float nll = lse - z[sl];
        if (valid) { vn += nll; vd += 1.f; }
    }
    #pragma unroll
    for (int off = 32; off; off >>= 1) { vn += __shfl_down(vn, off); vd += __shfl_down(vd, off); }
    __shared__ float rb[8];
    int wv = threadIdx.x >> 6;
    if ((threadIdx.x & 63) == 0) { rb[wv*2] = vn; rb[wv*2+1] = vd; }
    __syncthreads();
    if (threadIdx.x == 0) {
        atomicAdd(&acc[0], rb[0]+rb[2]+rb[4]+rb[6]);
        atomicAdd(&acc[1], rb[1]+rb[3]+rb[5]+rb[7]);
    }
}

// ---------------- projector: MFMA + L2-norm + featT + class-sum ----------------
__global__ __launch_bounds__(256) void proj_mfma(
    const u16* __restrict__ fea3b, const u16* __restrict__ wpt,
    const int* __restrict__ lab, u16* __restrict__ featT,
    float* __restrict__ csum)
{
    __shared__ float nrm[4][16];
    __shared__ float cs[256];        // [cls*128 + ch]
    int b = blockIdx.x;              // 0..399
    int n = b / 100;                 // 0..3 (unlabeled index)
    int px0 = (b - n*100) * 16;
    int t = threadIdx.x, lane = t & 63, wv = t >> 6;
    int idx15 = lane & 15, kg = lane >> 4;

    cs[t] = 0.f;

    const u16* fb = fea3b + ((size_t)(4+n)*1600 + px0) * 256;

    bf16x8 A[2][8];
    #pragma unroll
    for (int mi = 0; mi < 2; ++mi) {
        const u16* wrow = wpt + (size_t)(wv*32 + mi*16 + idx15)*256 + kg*8;
        #pragma unroll
        for (int ks = 0; ks < 8; ++ks)
            A[mi][ks] = *(const bf16x8*)(wrow + ks*32);
    }

    f32x4 acc[2];
    acc[0] = (f32x4){0.f,0.f,0.f,0.f};
    acc[1] = (f32x4){0.f,0.f,0.f,0.f};

    #pragma unroll
    for (int ks = 0; ks < 8; ++ks) {
        bf16x8 B = *(const bf16x8*)&fb[(size_t)idx15*256 + ks*32 + kg*8];
        acc[0] = __builtin_amdgcn_mfma_f32_16x16x32_bf16(A[0][ks], B, acc[0], 0, 0, 0);
        acc[1] = __builtin_amdgcn_mfma_f32_16x16x32_bf16(A[1][ks], B, acc[1], 0, 0, 0);
    }

    float sq = 0.f;
    #pragma unroll
    for (int mi = 0; mi < 2; ++mi)
        #pragma unroll
        for (int r = 0; r < 4; ++r) sq += acc[mi][r]*acc[mi][r];
    sq += __shfl_xor(sq, 16);
    sq += __shfl_xor(sq, 32);
    if (kg == 0) nrm[wv][idx15] = sq;
    __syncthreads();

    float tot = nrm[0][idx15] + nrm[1][idx15] + nrm[2][idx15] + nrm[3][idx15];
    float scale = 1.f / fmaxf(sqrtf(tot), 1e-12f);
    int rr = px0 + idx15;
    int yy = rr / 40, xx = rr - yy*40;
    int row = ((yy/10*4 + xx/10)*4 + n)*100 + (yy%10)*10 + (xx%10);
    int la = lab[row];
    int jt = row >> 4, rl = row & 15;
    u16* base = featT + (size_t)jt*2048;
    #pragma unroll
    for (int mi = 0; mi < 2; ++mi) {
        #pragma unroll
        for (int pr = 0; pr < 2; ++pr) {
            float v0 = acc[mi][2*pr]*scale, v1 = acc[mi][2*pr+1]*scale;
            unsigned int pk = (unsigned int)f2bf(v0) | ((unsigned int)f2bf(v1) << 16);
            int q = kg*4 + 2*pr;                  // channel within mi group (even)
            int g = wv*4 + mi*2 + (q >> 3);       // granule = c>>3
            *(unsigned int*)&base[(g*16 + rl)*8 + (q & 7)] = pk;
            int ch = wv*32 + mi*16 + q;           // global channel
            atomicAdd(&cs[la*128 + ch],     v0);
            atomicAdd(&cs[la*128 + ch + 1], v1);
        }
    }
    __syncthreads();
    atomicAdd(&csum[t], cs[t]);
}

// ---------------- EMA scatter -> featT + class-sum + 1 atomicMax/block ----------------
__global__ __launch_bounds__(256) void ema_scatter(
    const float* __restrict__ ema, const int* __restrict__ lab,
    u16* __restrict__ featT, float* __restrict__ csum,
    unsigned int* __restrict__ maxn)
{
    __shared__ float lds[128*64];    // 32 KB, col = pxl ^ ((c>>5)<<3)
    __shared__ float cs[256];        // [cls*128 + ch]
    int b = blockIdx.x;              // 0..99
    int n = b / 25;
    int r0 = (b - n*25) * 64;
    int t = threadIdx.x, lane = t & 63, wv = t >> 6;

    cs[t] = 0.f;

    const float* src = ema + ((size_t)n*128 + wv*32)*1600 + r0 + lane;
    int scol = lane ^ (wv << 3);
    #pragma unroll
    for (int cc = 0; cc < 32; ++cc)
        lds[(wv*32 + cc)*64 + scol] = src[(size_t)cc*1600];
    __syncthreads();

    int pxl = t >> 2, cq = t & 3;
    int r = r0 + pxl;
    int yy = r / 40, xx = r - yy*40;
    int row = 6400 + ((yy/10*4 + xx/10)*4 + n)*100 + (yy%10)*10 + (xx%10);
    int la = lab[row];
    int rcol = pxl ^ (cq << 3);
    float sq = 0.f;
    unsigned int pk[16];
    #pragma unroll
    for (int i = 0; i < 16; ++i) {
        float v0 = lds[(cq*32 + 2*i)*64 + rcol];
        float v1 = lds[(cq*32 + 2*i + 1)*64 + rcol];
        sq += v0*v0 + v1*v1;
        pk[i] = (unsigned int)f2bf(v0) | ((unsigned int)f2bf(v1) << 16);
        atomicAdd(&cs[la*128 + cq*32 + 2*i],     v0);
        atomicAdd(&cs[la*128 + cq*32 + 2*i + 1], v1);
    }
    int jt = row >> 4, rl = row & 15;
    u16* base = featT + (size_t)jt*2048;
    #pragma unroll
    for (int k8 = 0; k8 < 4; ++k8) {
        int g = cq*4 + k8;
        *(uint4*)&base[(g*16 + rl)*8] = *(uint4*)&pk[k8*4];
    }

    sq += __shfl_xor(sq, 1);
    sq += __shfl_xor(sq, 2);
    float mx = sq;
    #pragma unroll
    for (int off = 4; off < 64; off <<= 1) mx = fmaxf(mx, __shfl_xor(mx, off));
    __shared__ float red[4];
    if (lane == 0) red[wv] = mx;
    __syncthreads();
    if (t == 0)
        atomicMax(maxn, __float_as_uint(fmaxf(fmaxf(red[0], red[1]),
                                              fmaxf(red[2], red[3]))));
    atomicAdd(&csum[t], cs[t]);
}

// ---------------- contrastive: barrier-free MFMA denominator GEMM on compact featT ----------------
__global__ __launch_bounds__(256) void contrast_sE(
    const u16* __restrict__ featT, const unsigned int* __restrict__ maxn,
    float* __restrict__ partials)
{
    int js = blockIdx.x;      // 0..49
    int p0 = blockIdx.y * 2;  // patches p0, p0+1
    int t = threadIdx.x, lane = t & 63, wv = t >> 6;
    int idx15 = lane & 15;
    int kg = lane >> 4;

    float M = 2.f * sqrtf(__uint_as_float(*maxn)) + 4.f;
    float M2 = M * 1.44269504f;

    bf16x8 A[2][2][4];
    bf16x8 zz = {0,0,0,0,0,0,0,0};
    #pragma unroll
    for (int pi = 0; pi < 2; ++pi) {
        #pragma unroll
        for (int mi = 0; mi < 2; ++mi) {
            int m = wv + mi*4;
            #pragma unroll
            for (int c = 0; c < 4; ++c) {
                int a = 16*m + idx15;
                if (m < 7 && a < 100) {
                    int row = (p0+pi)*100 + a;
                    A[pi][mi][c] = *(const bf16x8*)&featT[
                        (size_t)(row >> 4)*2048 + (((c*4 + kg)*16 + (row & 15)))*8];
                } else A[pi][mi][c] = zz;
            }
        }
    }

    float sE[2][8] = {};
    const u16* jb = featT + (size_t)(js*16)*2048 + (size_t)(kg*16 + idx15)*8;

    bf16x8 Bc[4], Bn[4];
    #pragma unroll
    for (int c = 0; c < 4; ++c)
        Bc[c] = *(const bf16x8*)(jb + c*512);

    for (int jt = 0; jt < 16; ++jt) {
        if (jt < 15) {
            #pragma unroll
            for (int c = 0; c < 4; ++c)
                Bn[c] = *(const bf16x8*)(jb + (size_t)(jt+1)*2048 + c*512);
        }

        #pragma unroll
        for (int pi = 0; pi < 2; ++pi) {
            #pragma unroll
            for (int mi = 0; mi < 2; ++mi) {
                int m = wv + mi*4;
                if (m < 7) {
                    f32x4 C = {0.f, 0.f, 0.f, 0.f};
                    #pragma unroll
                    for (int c = 0; c < 4; ++c)
                        C = __builtin_amdgcn_mfma_f32_16x16x32_bf16(A[pi][mi][c], Bc[c], C, 0, 0, 0);
                    #pragma unroll
                    for (int rr = 0; rr < 4; ++rr)
                        sE[pi][mi*4+rr] += __builtin_amdgcn_exp2f(C[rr] * 2.885390082f - M2);
                }
            }
        }
        #pragma unroll
        for (int c = 0; c < 4; ++c) Bc[c] = Bn[c];
    }

    #pragma unroll
    for (int pi = 0; pi < 2; ++pi) {
        #pragma unroll
        for (int mi = 0; mi < 2; ++mi) {
            int m = wv + mi*4;
            if (m < 7) {
                #pragma unroll
                for (int r = 0; r < 4; ++r) {
                    float s = sE[pi][mi*4+r];
                    #pragma unroll
                    for (int off = 1; off < 16; off <<= 1)
                        s += __shfl_xor(s, off);
                    if (idx15 == 0) {
                        int a = 16*m + 4*kg + r;
                        partials[((size_t)(p0+pi)*NJS + js)*112 + a] = s;
                    }
                }
            }
        }
    }
}

// ---------------- merge: LSE + positive-sum via class sums (featT reads) ----------------
__global__ __launch_bounds__(128) void merge_contrast(
    const float* __restrict__ partials, const float* __restrict__ fc_cnt,
    const unsigned int* __restrict__ maxn, const u16* __restrict__ featT,
    const int* __restrict__ lab, const float* __restrict__ csum,
    float* __restrict__ acc)
{
    int p = blockIdx.x, t = threadIdx.x;
    float pa = 0.f;
    if (t < 100) {
        float s = 0.f;
        for (int js = 0; js < NJS; ++js)
            s += partials[((size_t)p*NJS + js)*112 + t];
        int row = p*100 + t;
        int la = lab[row];
        const float* Sv = csum + la*128;
        int jt = row >> 4, rl = row & 15;
        const u16* base = featT + (size_t)jt*2048;
        float dp = 0.f;
        #pragma unroll
        for (int i = 0; i < 64; ++i) {   // channel pair (2i, 2i+1)
            unsigned int pk = *(const unsigned int*)&base[((i >> 2)*16 + rl)*8 + (i & 3)*2];
            dp += __uint_as_float(pk << 16) * Sv[2*i]
                + __uint_as_float(pk & 0xffff0000u) * Sv[2*i+1];
        }
        float N1 = acc[8];
        float cnt = la ? N1 : (12800.f - N1);
        float M = 2.f * sqrtf(__uint_as_float(*maxn)) + 4.f;
        pa = M + logf(s) - 2.f * dp / fmaxf(cnt, 1.f);
    }
    #pragma unroll
    for (int off = 32; off; off >>= 1) pa += __shfl_down(pa, off);
    __shared__ float w2[2];
    if ((t & 63) == 0) w2[t >> 6] = pa;
    __syncthreads();
    if (t == 0) {
        float loss_p = (w2[0] + w2[1]) / 100.f;
        float fcv = fc_cnt[p] / 100.f;
        float inc = ((fcv > 0.1f) && (fcv < 0.9f)) ? 0.f : 1.f;
        atomicAdd(&acc[5], loss_p * inc);
        atomicAdd(&acc[6], inc);
    }
}

// ---------------- final combine ----------------
__global__ void final_kernel(const float* __restrict__ acc,
                             const int* __restrict__ epoch_p,
                             float* __restrict__ out)
{
    if (threadIdx.x == 0 && blockIdx.x == 0) {
        float loss_sup = acc[0] / fmaxf(acc[1], 1.f);
        int epoch = *epoch_p;
        float loss = loss_sup;
        if (epoch >= 5) {
            float contr = acc[5] / fmaxf(acc[6], 1.f);
            float cons  = acc[3] / fmaxf(acc[4], 1.f);
            float ent   = acc[2] / 6400.f;
            float ramp  = fminf(fmaxf((float)epoch / 40.f, 0.f), 1.f);
            float d = 1.f - ramp;
            float cons_w = expf(-5.f * d * d);
            loss = loss_sup + 0.1f * contr + cons_w * cons + 0.01f * ent;
        }
        out[0] = loss;
    }
}

extern "C" void kernel_launch(void* const* d_in, const int* in_sizes, int n_in,
                              void* d_out, int out_size, void* d_ws, size_t ws_size,
                              hipStream_t stream)
{
    const float* x_l      = (const float*)d_in[0];
    const int*   y_l      = (const int*)  d_in[1];
    const float* x_ul     = (const float*)d_in[2];
    const int*   epoch    = (const int*)  d_in[3];
    const float* proj_ema = (const float*)d_in[4];
    const float* z_ema    = (const float*)d_in[5];
    const float* W1       = (const float*)d_in[6];
    const float* W2       = (const float*)d_in[7];
    const float* W3       = (const float*)d_in[8];
    const float* Wc       = (const float*)d_in[9];
    const float* bc       = (const float*)d_in[10];
    const float* Wp       = (const float*)d_in[11];
    float* out = (float*)d_out;
    float* ws  = (float*)d_ws;

    u16*   fea1b = (u16*)(ws + WS_FEA1B);
    u16*   fea2b = (u16*)(ws + WS_FEA2B);
    u16*   fea3b = (u16*)(ws + WS_FEA3B);
    float* zls   = ws + WS_ZLS;
    u16*   featT = (u16*)(ws + WS_FEATT);
    int*   labA  = (int*)(ws + WS_LAB);
    float* part  = ws + WS_PART;
    float* acc   = ws + WS_ACC;
    float* fc    = ws + WS_FC;
    float* csum  = ws + WS_CSUM;
    u16*   wt2   = (u16*)(ws + WS_WT2);
    u16*   wt3   = (u16*)(ws + WS_WT3);
    u16*   wpt   = (u16*)(ws + WS_WPT);
    unsigned int* maxn = (unsigned int*)(acc + 7);

    wtrans<<<1568, 256, 0, stream>>>(W2, W3, Wp, wt2, wt3, wpt, acc);

    // ---- both branches batched (n 0..3 labeled, 4..7 unlabeled) ----
    conv1_k<<<dim3(160, 8), 256, 0, stream>>>(x_l, x_ul, W1, fea1b);
    conv3x3_nhwc<64,128,160,80,2><<<dim3(100, 1, 8), 256, 0, stream>>>(fea1b, wt2, fea2b);
    conv3x3_nhwc<128,256,80,40,2><<<dim3(25, 2, 8), 256, 0, stream>>>(fea2b, wt3, fea3b);

    cls_ul_fused<<<200, 256, 0, stream>>>(fea3b, Wc, bc, z_ema, zls, labA, acc, fc);
    loss_sup_kernel<<<512, 256, 0, stream>>>(zls, y_l, bc, acc);

    proj_mfma<<<400, 256, 0, stream>>>(fea3b, wpt, labA, featT, csum);
    ema_scatter<<<100, 256, 0, stream>>>(proj_ema, labA, featT, csum, maxn);

    contrast_sE<<<dim3(NJS, 32), 256, 0, stream>>>(featT, maxn, part);
    merge_contrast<<<64, 128, 0, stream>>>(part, fc, maxn, featT, labA, csum, acc);
    final_kernel<<<1, 64, 0, stream>>>(acc, epoch, out);
}

// Round 20
// 197.309 us; speedup vs baseline: 1.0649x; 1.0649x over previous
//
#include <hip/hip_runtime.h>
#include <math.h>

typedef unsigned short u16;
typedef __attribute__((ext_vector_type(8))) short bf16x8;
typedef __attribute__((ext_vector_type(4))) float f32x4;

// ---------------- workspace layout (float-element offsets) ----------------
static const size_t WS_FEA1B = 0;          // 8*160*160*64 bf16 NHWC -> 6,553,600 floats
static const size_t WS_FEA2B = 6553600;    // 8*80*80*128 bf16 NHWC -> 3,276,800
static const size_t WS_FEA3B = 9830400;    // 8*40*40*256 bf16 NHWC -> 1,638,400
static const size_t WS_ZLS   = 11468800;   // 12,800
static const size_t WS_FEATT = 11481600;   // K-major feat: 800 jt * 2048 u16 (region reserves 2x)
static const size_t WS_LAB   = 13120000;   // 12,800 int
static const size_t WS_PART  = 13132800;   // 64*50*112 = 358,400
static const size_t WS_ACC   = 13491200;   // 16 floats (acc[7]=maxnorm2 bits, acc[8]=N1)
static const size_t WS_FC    = 13491216;   // 64
static const size_t WS_CSUM  = 13491280;   // 256
static const size_t WS_WT2   = 13491536;   // 36,864
static const size_t WS_WT3   = 13528400;   // 147,456
static const size_t WS_WPT   = 13675856;   // 16,384
// end 13,692,240 floats = 54.8 MB

#define NJS 50   // contrast j-splits; 256 j per block = 16 jt tiles

// featT element (row j, channel c) at u16 index (COMPACT, fully dense):
//   (j>>4)*2048 + ((c>>3)*16 + (j&15))*8 + (c&7)

__device__ inline u16 f2bf(float x) {
    unsigned int u = __float_as_uint(x);
    unsigned int r = u + 0x7fffu + ((u >> 16) & 1u);
    return (u16)(r >> 16);
}
__device__ inline float bf2f(u16 v) {
    return __uint_as_float((unsigned int)v << 16);
}

// ---------------- weight transform + accumulator zeroing ----------------
__global__ __launch_bounds__(256) void wtrans(
    const float* __restrict__ W2, const float* __restrict__ W3,
    const float* __restrict__ Wp,
    u16* __restrict__ wt2, u16* __restrict__ wt3, u16* __restrict__ wpt,
    float* __restrict__ accz)
{
    int tid = blockIdx.x * 256 + threadIdx.x;
    if (blockIdx.x == 0) {
        for (int i = threadIdx.x; i < 336; i += 256)   // acc(16)+fc(64)+csum(256)
            accz[i] = 0.f;
    }
    if (tid < 73728) {               // W2: Co=128, Ci=64
        int ci = tid & 63, rest = tid >> 6;
        int co = rest & 127, tap = rest >> 7;
        wt2[tid] = f2bf(W2[((size_t)co*64 + ci)*9 + tap]);
    } else if (tid < 368640) {       // W3: Co=256, Ci=128
        int t3 = tid - 73728;
        int ci = t3 & 127, rest = t3 >> 7;
        int co = rest & 255, tap = rest >> 8;
        wt3[t3] = f2bf(W3[((size_t)co*128 + ci)*9 + tap]);
    } else {                         // Wp: [128][256]
        int tp = tid - 368640;
        wpt[tp] = f2bf(Wp[tp]);
    }
}

// ---------------- conv1: 3->64, 320->160, NHWC bf16 out ----------------
__global__ __launch_bounds__(256) void conv1_k(
    const float* __restrict__ x_l, const float* __restrict__ x_ul,
    const float* __restrict__ W1, u16* __restrict__ fea1b)
{
    int oy = blockIdx.x;
    int n  = blockIdx.y;
    const float* x = (n < 4) ? x_l + (size_t)n*307200
                             : x_ul + (size_t)(n-4)*307200;
    int t = threadIdx.x;
    int co = t & 63, g = t >> 6;
    __shared__ float lds[9*324];
    for (int u = t; u < 9*322; u += 256) {
        int plane = u / 322, col = u - plane*322;
        int ci = plane / 3, ky = plane - ci*3;
        int iy = oy*2 + ky;
        float v = 0.f;
        if (iy < 320 && col < 320)
            v = x[((size_t)ci*320 + iy)*320 + col];
        lds[plane*324 + col] = v;
    }
    __syncthreads();
    float w[27];
    #pragma unroll
    for (int k = 0; k < 27; ++k) w[k] = W1[co*27 + k];
    float acc[40];
    #pragma unroll
    for (int i = 0; i < 40; ++i) acc[i] = 0.f;
    #pragma unroll
    for (int ci = 0; ci < 3; ++ci) {
        #pragma unroll
        for (int ky = 0; ky < 3; ++ky) {
            const float* base = &lds[(ci*3+ky)*324 + g*80];
            const float* wk = &w[(ci*3+ky)*3];
            #pragma unroll
            for (int q = 0; q < 10; ++q) {
                float4 a = *(const float4*)&base[q*8];
                float4 b = *(const float4*)&base[q*8+4];
                float2 c = *(const float2*)&base[q*8+8];
                float xx[10] = {a.x,a.y,a.z,a.w,b.x,b.y,b.z,b.w,c.x,c.y};
                #pragma unroll
                for (int oo = 0; oo < 4; ++oo)
                    acc[q*4+oo] += wk[0]*xx[2*oo] + wk[1]*xx[2*oo+1] + wk[2]*xx[2*oo+2];
            }
        }
    }
    u16* dst = fea1b + (((size_t)n*160 + oy)*160 + g*40)*64 + co;
    #pragma unroll
    for (int i = 0; i < 40; ++i)
        dst[(size_t)i*64] = f2bf(fmaxf(acc[i], 0.f));
}

// ---------------- implicit-GEMM MFMA conv 3x3 s2 (+ReLU), NHWC in/out ----------------
template<int Ci, int Co, int H, int OH, int COG>
__global__ __launch_bounds__(256) void conv3x3_nhwc(
    const u16* __restrict__ inb, const u16* __restrict__ wt,
    u16* __restrict__ outb)
{
    constexpr int TILES = OH/8;
    int tile = blockIdx.x;
    int co0  = blockIdx.y * (64*COG);
    int n    = blockIdx.z;
    int ty = tile / TILES, tx = tile - ty*TILES;
    int oy0 = ty*8, ox0 = tx*8;
    int iy0 = oy0*2, ix0 = ox0*2;
    int t = threadIdx.x, lane = t & 63, wv = t >> 6;
    int idx15 = lane & 15, kg = lane >> 4;

    __shared__ u16 lds[306*40];   // 24,480 B

    f32x4 acc[COG][4];
    #pragma unroll
    for (int cog = 0; cog < COG; ++cog)
        #pragma unroll
        for (int nt = 0; nt < 4; ++nt) acc[cog][nt] = (f32x4){0.f,0.f,0.f,0.f};

    int goff[5], loff[5];
    #pragma unroll
    for (int i = 0; i < 5; ++i) {
        int u = t + i*256;
        if (u < 1224) {
            int pix = u >> 2, q = u & 3;
            int iyl = pix / 18, j = pix - iyl*18;
            int iy = iy0 + iyl, ix = ix0 + j;
            bool ok = (iy < H && ix < H);
            goff[i] = ok ? (((n*H + iy)*H + ix)*Ci + q*8) : -1;
            int jp = (j & 1)*9 + (j >> 1);
            loff[i] = (iyl*18 + jp)*40 + q*8;
        } else goff[i] = -2;
    }
    uint4 vreg[5];
    #pragma unroll
    for (int i = 0; i < 5; ++i) {
        if (goff[i] == -2) continue;
        vreg[i] = (goff[i] >= 0) ? *(const uint4*)&inb[(size_t)goff[i]]
                                 : make_uint4(0,0,0,0);
    }

    for (int c0 = 0; c0 < Ci; c0 += 32) {
        __syncthreads();
        #pragma unroll
        for (int i = 0; i < 5; ++i)
            if (goff[i] != -2) *(uint4*)&lds[loff[i]] = vreg[i];
        __syncthreads();
        if (c0 + 32 < Ci) {
            #pragma unroll
            for (int i = 0; i < 5; ++i) {
                if (goff[i] == -2) continue;
                vreg[i] = (goff[i] >= 0) ? *(const uint4*)&inb[(size_t)goff[i] + c0 + 32]
                                         : make_uint4(0,0,0,0);
            }
        }

        bf16x8 A[COG][9];
        #pragma unroll
        for (int cog = 0; cog < COG; ++cog) {
            const u16* wb = wt + (size_t)(co0 + cog*64 + wv*16 + idx15)*Ci + c0 + kg*8;
            #pragma unroll
            for (int tap = 0; tap < 9; ++tap)
                A[cog][tap] = *(const bf16x8*)(wb + (size_t)tap*Co*Ci);
        }

        #pragma unroll
        for (int tap = 0; tap < 9; ++tap) {
            int ky = tap/3, kx = tap - ky*3;
            #pragma unroll
            for (int nt = 0; nt < 4; ++nt) {
                int l = nt*16 + idx15;
                int iyl = 2*(l>>3) + ky;
                int j = 2*(l&7) + kx;
                int jp = (j&1)*9 + (j>>1);
                bf16x8 B = *(const bf16x8*)&lds[(size_t)(iyl*18 + jp)*40 + kg*8];
                #pragma unroll
                for (int cog = 0; cog < COG; ++cog)
                    acc[cog][nt] = __builtin_amdgcn_mfma_f32_16x16x32_bf16(A[cog][tap], B, acc[cog][nt], 0, 0, 0);
            }
        }
    }

    #pragma unroll
    for (int cog = 0; cog < COG; ++cog) {
        int co = co0 + cog*64 + wv*16 + kg*4;
        #pragma unroll
        for (int nt = 0; nt < 4; ++nt) {
            int l = nt*16 + idx15;
            int oy = oy0 + (l>>3), ox = ox0 + (l&7);
            u16* dst = outb + (((size_t)n*OH + oy)*OH + ox)*Co + co;
            unsigned int p0 = (unsigned int)f2bf(fmaxf(acc[cog][nt][0],0.f))
                            | ((unsigned int)f2bf(fmaxf(acc[cog][nt][1],0.f)) << 16);
            unsigned int p1 = (unsigned int)f2bf(fmaxf(acc[cog][nt][2],0.f))
                            | ((unsigned int)f2bf(fmaxf(acc[cog][nt][3],0.f)) << 16);
            *(uint2*)dst = make_uint2(p0, p1);
        }
    }
}

// ---------------- fused 1x1 classifier + unlabeled losses (4 threads/px) ----------------
__global__ __launch_bounds__(256) void cls_ul_fused(
    const u16* __restrict__ feab, const float* __restrict__ Wc,
    const float* __restrict__ bc, const float* __restrict__ z_ema,
    float* __restrict__ zls, int* __restrict__ lab_all,
    float* __restrict__ acc, float* __restrict__ fc_cnt)
{
    int gid = blockIdx.x * 256 + threadIdx.x;   // 51200 = 12800 px * 4
    int px = gid >> 2, part = gid & 3;
    int n = px / 1600, r = px - n*1600;
    const u16* f = feab + (size_t)px * 256 + part*64;
    const float* w0 = Wc + part*64;
    const float* w1 = Wc + 256 + part*64;
    float a0 = 0.f, a1 = 0.f;
    #pragma unroll
    for (int ci = 0; ci < 64; ci += 8) {
        bf16x8 v = *(const bf16x8*)&f[ci];
        #pragma unroll
        for (int j = 0; j < 8; ++j) {
            float x = bf2f((u16)v[j]);
            a0 += x * w0[ci+j];
            a1 += x * w1[ci+j];
        }
    }
    a0 += __shfl_xor(a0, 1); a0 += __shfl_xor(a0, 2);
    a1 += __shfl_xor(a1, 1); a1 += __shfl_xor(a1, 2);

    float ent = 0.f, cn = 0.f, cd = 0.f;
    if (part == 0) {
        if (n < 4) {
            zls[(size_t)n*3200 + r]        = a0;
            zls[(size_t)n*3200 + 1600 + r] = a1;
        } else {
            int nu = n - 4;
            float z0 = a0 + bc[0], z1 = a1 + bc[1];
            float m = fmaxf(z0, z1);
            float e0 = expf(z0 - m), e1 = expf(z1 - m);
            float lse = m + logf(e0 + e1);
            float lp0 = z0 - lse, lp1 = z1 - lse;
            float p0 = expf(lp0), p1 = expf(lp1);
            ent = -(p0*lp0 + p1*lp1);
            int pl = (z1 > z0) ? 1 : 0;
            float ze0 = z_ema[(size_t)nu*3200 + r], ze1 = z_ema[(size_t)nu*3200 + 1600 + r];
            float me = fmaxf(ze0, ze1);
            float f0 = expf(ze0 - me), f1 = expf(ze1 - me);
            float maxp = 1.f / (f0 + f1);
            int ple = (ze1 > ze0) ? 1 : 0;
            bool mask = (maxp > 0.6f);
            float nll = lse - (ple ? z1 : z0);

            int yy = r / 40, xx = r - yy*40;
            int pi = yy / 10, hi = yy % 10, pj = xx / 10, wi = xx % 10;
            int patch = (pi*4 + pj)*4 + nu;
            int row = patch * 100 + hi*10 + wi;
            lab_all[row]        = pl;
            lab_all[6400 + row] = ple;
            atomicAdd(&fc_cnt[patch], (float)pl);
            cn = mask ? nll : 0.f;
            cd = mask ? 1.f : 0.f;
        }
    }
    #pragma unroll
    for (int off = 32; off; off >>= 1) {
        ent += __shfl_down(ent, off);
        cn  += __shfl_down(cn, off);
        cd  += __shfl_down(cd, off);
    }
    if ((threadIdx.x & 63) == 0 && (ent != 0.f || cd != 0.f)) {
        atomicAdd(&acc[2], ent);
        atomicAdd(&acc[3], cn);
        atomicAdd(&acc[4], cd);
    }
}

// ---------------- supervised CE: grid-stride + block reduce ----------------
__global__ __launch_bounds__(256) void loss_sup_kernel(
    const float* __restrict__ zs, const int* __restrict__ y,
    const float* __restrict__ bc, float* __restrict__ acc)
{
    const float step = 39.0f / 319.0f;
    float b0 = bc[0], b1 = bc[1];
    float vn = 0.f, vd = 0.f;
    for (int idx = blockIdx.x*256 + threadIdx.x; idx < 409600; idx += gridDim.x*256) {
        int n  = idx / 102400;
        int r  = idx - n*102400;
        int oy = r / 320, ox = r - oy*320;
        float ty = (float)oy * step, tx = (float)ox * step;
        int y0 = (int)ty, x0 = (int)tx;
        int y1 = min(y0 + 1, 39), x1 = min(x0 + 1, 39);
        float wy = ty - (float)y0, wx = tx - (float)x0;
        const float* base = zs + (size_t)n * 3200;
        float z[2];
        #pragma unroll
        for (int c = 0; c < 2; ++c) {
            const float* pl = base + c * 1600;
            float v00 = pl[y0*40 + x0], v01 = pl[y0*40 + x1];
            float v10 = pl[y1*40 + x0], v11 = pl[y1*40 + x1];
            float top = v00 * (1.f - wx) + v01 * wx;
            float bot = v10 * (1.f - wx) + v11 * wx;
            z[c] = top * (1.f - wy) + bot * wy + (c ? b1 : b0);
        }
        int lab = y[idx];
        bool valid = (lab != 255);
        int sl = min(max(lab, 0), 1);
        float mz  = fmaxf(z[0], z[1]);
        float lse = mz + logf(expf(z[0]-mz) + expf(z[1]-mz));
        float nll = lse - z[sl];
        if (valid) { vn += nll; vd += 1.f; }
    }
    #pragma unroll
    for (int off = 32; off; off >>= 1) { vn += __shfl_down(vn, off); vd += __shfl_down(vd, off); }
    __shared__ float rb[8];
    int wv = threadIdx.x >> 6;
    if ((threadIdx.x & 63) == 0) { rb[wv*2] = vn; rb[wv*2+1] = vd; }
    __syncthreads();
    if (threadIdx.x == 0) {
        atomicAdd(&acc[0], rb[0]+rb[2]+rb[4]+rb[6]);
        atomicAdd(&acc[1], rb[1]+rb[3]+rb[5]+rb[7]);
    }
}

// ---------------- projector: bf16 NHWC in, MFMA, L2-norm, featT out ----------------
__global__ __launch_bounds__(256) void proj_mfma(
    const u16* __restrict__ fea3b, const u16* __restrict__ wpt,
    u16* __restrict__ featT)
{
    __shared__ float nrm[4][16];
    int b = blockIdx.x;              // 0..399
    int n = b / 100;                 // 0..3 (unlabeled index)
    int px0 = (b - n*100) * 16;
    int t = threadIdx.x, lane = t & 63, wv = t >> 6;
    int idx15 = lane & 15, kg = lane >> 4;

    const u16* fb = fea3b + ((size_t)(4+n)*1600 + px0) * 256;

    bf16x8 A[2][8];
    #pragma unroll
    for (int mi = 0; mi < 2; ++mi) {
        const u16* wrow = wpt + (size_t)(wv*32 + mi*16 + idx15)*256 + kg*8;
        #pragma unroll
        for (int ks = 0; ks < 8; ++ks)
            A[mi][ks] = *(const bf16x8*)(wrow + ks*32);
    }

    f32x4 acc[2];
    acc[0] = (f32x4){0.f,0.f,0.f,0.f};
    acc[1] = (f32x4){0.f,0.f,0.f,0.f};

    #pragma unroll
    for (int ks = 0; ks < 8; ++ks) {
        bf16x8 B = *(const bf16x8*)&fb[(size_t)idx15*256 + ks*32 + kg*8];
        acc[0] = __builtin_amdgcn_mfma_f32_16x16x32_bf16(A[0][ks], B, acc[0], 0, 0, 0);
        acc[1] = __builtin_amdgcn_mfma_f32_16x16x32_bf16(A[1][ks], B, acc[1], 0, 0, 0);
    }

    float sq = 0.f;
    #pragma unroll
    for (int mi = 0; mi < 2; ++mi)
        #pragma unroll
        for (int r = 0; r < 4; ++r) sq += acc[mi][r]*acc[mi][r];
    sq += __shfl_xor(sq, 16);
    sq += __shfl_xor(sq, 32);
    if (kg == 0) nrm[wv][idx15] = sq;
    __syncthreads();

    float tot = nrm[0][idx15] + nrm[1][idx15] + nrm[2][idx15] + nrm[3][idx15];
    float scale = 1.f / fmaxf(sqrtf(tot), 1e-12f);
    int rr = px0 + idx15;
    int yy = rr / 40, xx = rr - yy*40;
    int row = ((yy/10*4 + xx/10)*4 + n)*100 + (yy%10)*10 + (xx%10);
    int jt = row >> 4, rl = row & 15;
    u16* base = featT + (size_t)jt*2048;
    #pragma unroll
    for (int mi = 0; mi < 2; ++mi) {
        #pragma unroll
        for (int pr = 0; pr < 2; ++pr) {
            unsigned int pk = (unsigned int)f2bf(acc[mi][2*pr]*scale)
                            | ((unsigned int)f2bf(acc[mi][2*pr+1]*scale) << 16);
            int q = kg*4 + 2*pr;                  // channel within mi group (even)
            int g = wv*4 + mi*2 + (q >> 3);       // granule = c>>3
            *(unsigned int*)&base[(g*16 + rl)*8 + (q & 7)] = pk;
        }
    }
}

// ---------------- EMA scatter -> featT + 1 atomicMax/block ----------------
__global__ __launch_bounds__(256) void ema_scatter(
    const float* __restrict__ ema, u16* __restrict__ featT,
    unsigned int* __restrict__ maxn)
{
    __shared__ float lds[128*64];    // 32 KB, col = pxl ^ ((c>>5)<<3)
    int b = blockIdx.x;              // 0..99
    int n = b / 25;
    int r0 = (b - n*25) * 64;
    int t = threadIdx.x, lane = t & 63, wv = t >> 6;

    const float* src = ema + ((size_t)n*128 + wv*32)*1600 + r0 + lane;
    int scol = lane ^ (wv << 3);
    #pragma unroll
    for (int cc = 0; cc < 32; ++cc)
        lds[(wv*32 + cc)*64 + scol] = src[(size_t)cc*1600];
    __syncthreads();

    int pxl = t >> 2, cq = t & 3;
    int r = r0 + pxl;
    int yy = r / 40, xx = r - yy*40;
    int row = 6400 + ((yy/10*4 + xx/10)*4 + n)*100 + (yy%10)*10 + (xx%10);
    int rcol = pxl ^ (cq << 3);
    float sq = 0.f;
    unsigned int pk[16];
    #pragma unroll
    for (int i = 0; i < 16; ++i) {
        float v0 = lds[(cq*32 + 2*i)*64 + rcol];
        float v1 = lds[(cq*32 + 2*i + 1)*64 + rcol];
        sq += v0*v0 + v1*v1;
        pk[i] = (unsigned int)f2bf(v0) | ((unsigned int)f2bf(v1) << 16);
    }
    int jt = row >> 4, rl = row & 15;
    u16* base = featT + (size_t)jt*2048;
    #pragma unroll
    for (int k8 = 0; k8 < 4; ++k8) {
        int g = cq*4 + k8;
        *(uint4*)&base[(g*16 + rl)*8] = *(uint4*)&pk[k8*4];
    }

    sq += __shfl_xor(sq, 1);
    sq += __shfl_xor(sq, 2);
    float mx = sq;
    #pragma unroll
    for (int off = 4; off < 64; off <<= 1) mx = fmaxf(mx, __shfl_xor(mx, off));
    __shared__ float red[4];
    if (lane == 0) red[wv] = mx;
    __syncthreads();
    if (t == 0)
        atomicMax(maxn, __float_as_uint(fmaxf(fmaxf(red[0], red[1]),
                                              fmaxf(red[2], red[3]))));
}

// ---------------- class feature sums + label-1 count (128 blocks) ----------------
__global__ __launch_bounds__(256) void class_sum(
    const u16* __restrict__ featT, const int* __restrict__ lab,
    float* __restrict__ csum, float* __restrict__ acc)
{
    int t = threadIdx.x;
    int chp = t & 63;        // channel pair (2*chp, 2*chp+1)
    int s   = t >> 6;        // 0..3
    int r0 = blockIdx.x * 100;
    int g = chp >> 2, go = (chp & 3) * 2;
    float s00=0.f, s01=0.f, s10=0.f, s11=0.f;
    float c1 = 0.f;
    for (int i = s; i < 100; i += 4) {
        int row = r0 + i;
        int jt = row >> 4, rl = row & 15;
        unsigned int pk = *(const unsigned int*)&featT[(size_t)jt*2048 + (g*16 + rl)*8 + go];
        float v0 = __uint_as_float(pk << 16);
        float v1 = __uint_as_float(pk & 0xffff0000u);
        int la = lab[row];
        if (la) { s10 += v0; s11 += v1; }
        else    { s00 += v0; s01 += v1; }
        if (chp == 0) c1 += (float)la;
    }
    __shared__ float red[4][256];
    __shared__ float cbuf[4];
    red[s][chp*4+0] = s00; red[s][chp*4+1] = s01;
    red[s][chp*4+2] = s10; red[s][chp*4+3] = s11;
    if (chp == 0) cbuf[s] = c1;
    __syncthreads();
    if (s == 0) {
        #pragma unroll
        for (int k = 0; k < 4; ++k) {
            float v = red[0][chp*4+k] + red[1][chp*4+k] + red[2][chp*4+k] + red[3][chp*4+k];
            int cls = k >> 1, par = k & 1;
            atomicAdd(&csum[cls*128 + 2*chp + par], v);
        }
    }
    if (t == 0)
        atomicAdd(&acc[8], cbuf[0]+cbuf[1]+cbuf[2]+cbuf[3]);
}

// ---------------- contrastive: barrier-free MFMA denominator GEMM on compact featT ----------------
// grid (NJS=50, 32 patch-pairs). B loads fully dense: fixed c spans
// kg*128 + idx15*8 = contiguous 2KB per wave-instruction.
__global__ __launch_bounds__(256) void contrast_sE(
    const u16* __restrict__ featT, const unsigned int* __restrict__ maxn,
    float* __restrict__ partials)
{
    int js = blockIdx.x;      // 0..49
    int p0 = blockIdx.y * 2;  // patches p0, p0+1
    int t = threadIdx.x, lane = t & 63, wv = t >> 6;
    int idx15 = lane & 15;
    int kg = lane >> 4;

    float M = 2.f * sqrtf(__uint_as_float(*maxn)) + 4.f;
    float M2 = M * 1.44269504f;

    bf16x8 A[2][2][4];
    bf16x8 zz = {0,0,0,0,0,0,0,0};
    #pragma unroll
    for (int pi = 0; pi < 2; ++pi) {
        #pragma unroll
        for (int mi = 0; mi < 2; ++mi) {
            int m = wv + mi*4;
            #pragma unroll
            for (int c = 0; c < 4; ++c) {
                int a = 16*m + idx15;
                if (m < 7 && a < 100) {
                    int row = (p0+pi)*100 + a;
                    A[pi][mi][c] = *(const bf16x8*)&featT[
                        (size_t)(row >> 4)*2048 + (((c*4 + kg)*16 + (row & 15)))*8];
                } else A[pi][mi][c] = zz;
            }
        }
    }

    float sE[2][8] = {};
    const u16* jb = featT + (size_t)(js*16)*2048 + (size_t)(kg*16 + idx15)*8;

    bf16x8 Bc[4], Bn[4];
    #pragma unroll
    for (int c = 0; c < 4; ++c)
        Bc[c] = *(const bf16x8*)(jb + c*512);

    for (int jt = 0; jt < 16; ++jt) {
        if (jt < 15) {
            #pragma unroll
            for (int c = 0; c < 4; ++c)
                Bn[c] = *(const bf16x8*)(jb + (size_t)(jt+1)*2048 + c*512);
        }

        #pragma unroll
        for (int pi = 0; pi < 2; ++pi) {
            #pragma unroll
            for (int mi = 0; mi < 2; ++mi) {
                int m = wv + mi*4;
                if (m < 7) {
                    f32x4 C = {0.f, 0.f, 0.f, 0.f};
                    #pragma unroll
                    for (int c = 0; c < 4; ++c)
                        C = __builtin_amdgcn_mfma_f32_16x16x32_bf16(A[pi][mi][c], Bc[c], C, 0, 0, 0);
                    #pragma unroll
                    for (int rr = 0; rr < 4; ++rr)
                        sE[pi][mi*4+rr] += __builtin_amdgcn_exp2f(C[rr] * 2.885390082f - M2);
                }
            }
        }
        #pragma unroll
        for (int c = 0; c < 4; ++c) Bc[c] = Bn[c];
    }

    #pragma unroll
    for (int pi = 0; pi < 2; ++pi) {
        #pragma unroll
        for (int mi = 0; mi < 2; ++mi) {
            int m = wv + mi*4;
            if (m < 7) {
                #pragma unroll
                for (int r = 0; r < 4; ++r) {
                    float s = sE[pi][mi*4+r];
                    #pragma unroll
                    for (int off = 1; off < 16; off <<= 1)
                        s += __shfl_xor(s, off);
                    if (idx15 == 0) {
                        int a = 16*m + 4*kg + r;
                        partials[((size_t)(p0+pi)*NJS + js)*112 + a] = s;
                    }
                }
            }
        }
    }
}

// ---------------- merge: LSE + positive-sum via class sums (featT reads) ----------------
__global__ __launch_bounds__(128) void merge_contrast(
    const float* __restrict__ partials, const float* __restrict__ fc_cnt,
    const unsigned int* __restrict__ maxn, const u16* __restrict__ featT,
    const int* __restrict__ lab, const float* __restrict__ csum,
    float* __restrict__ acc)
{
    int p = blockIdx.x, t = threadIdx.x;
    float pa = 0.f;
    if (t < 100) {
        float s = 0.f;
        for (int js = 0; js < NJS; ++js)
            s += partials[((size_t)p*NJS + js)*112 + t];
        int row = p*100 + t;
        int la = lab[row];
        const float* Sv = csum + la*128;
        int jt = row >> 4, rl = row & 15;
        const u16* base = featT + (size_t)jt*2048;
        float dp = 0.f;
        #pragma unroll
        for (int i = 0; i < 64; ++i) {   // channel pair (2i, 2i+1)
            unsigned int pk = *(const unsigned int*)&base[((i >> 2)*16 + rl)*8 + (i & 3)*2];
            dp += __uint_as_float(pk << 16) * Sv[2*i]
                + __uint_as_float(pk & 0xffff0000u) * Sv[2*i+1];
        }
        float N1 = acc[8];
        float cnt = la ? N1 : (12800.f - N1);
        float M = 2.f * sqrtf(__uint_as_float(*maxn)) + 4.f;
        pa = M + logf(s) - 2.f * dp / fmaxf(cnt, 1.f);
    }
    #pragma unroll
    for (int off = 32; off; off >>= 1) pa += __shfl_down(pa, off);
    __shared__ float w2[2];
    if ((t & 63) == 0) w2[t >> 6] = pa;
    __syncthreads();
    if (t == 0) {
        float loss_p = (w2[0] + w2[1]) / 100.f;
        float fcv = fc_cnt[p] / 100.f;
        float inc = ((fcv > 0.1f) && (fcv < 0.9f)) ? 0.f : 1.f;
        atomicAdd(&acc[5], loss_p * inc);
        atomicAdd(&acc[6], inc);
    }
}

// ---------------- final combine ----------------
__global__ void final_kernel(const float* __restrict__ acc,
                             const int* __restrict__ epoch_p,
                             float* __restrict__ out)
{
    if (threadIdx.x == 0 && blockIdx.x == 0) {
        float loss_sup = acc[0] / fmaxf(acc[1], 1.f);
        int epoch = *epoch_p;
        float loss = loss_sup;
        if (epoch >= 5) {
            float contr = acc[5] / fmaxf(acc[6], 1.f);
            float cons  = acc[3] / fmaxf(acc[4], 1.f);
            float ent   = acc[2] / 6400.f;
            float ramp  = fminf(fmaxf((float)epoch / 40.f, 0.f), 1.f);
            float d = 1.f - ramp;
            float cons_w = expf(-5.f * d * d);
            loss = loss_sup + 0.1f * contr + cons_w * cons + 0.01f * ent;
        }
        out[0] = loss;
    }
}

extern "C" void kernel_launch(void* const* d_in, const int* in_sizes, int n_in,
                              void* d_out, int out_size, void* d_ws, size_t ws_size,
                              hipStream_t stream)
{
    const float* x_l      = (const float*)d_in[0];
    const int*   y_l      = (const int*)  d_in[1];
    const float* x_ul     = (const float*)d_in[2];
    const int*   epoch    = (const int*)  d_in[3];
    const float* proj_ema = (const float*)d_in[4];
    const float* z_ema    = (const float*)d_in[5];
    const float* W1       = (const float*)d_in[6];
    const float* W2       = (const float*)d_in[7];
    const float* W3       = (const float*)d_in[8];
    const float* Wc       = (const float*)d_in[9];
    const float* bc       = (const float*)d_in[10];
    const float* Wp       = (const float*)d_in[11];
    float* out = (float*)d_out;
    float* ws  = (float*)d_ws;

    u16*   fea1b = (u16*)(ws + WS_FEA1B);
    u16*   fea2b = (u16*)(ws + WS_FEA2B);
    u16*   fea3b = (u16*)(ws + WS_FEA3B);
    float* zls   = ws + WS_ZLS;
    u16*   featT = (u16*)(ws + WS_FEATT);
    int*   labA  = (int*)(ws + WS_LAB);
    float* part  = ws + WS_PART;
    float* acc   = ws + WS_ACC;
    float* fc    = ws + WS_FC;
    float* csum  = ws + WS_CSUM;
    u16*   wt2   = (u16*)(ws + WS_WT2);
    u16*   wt3   = (u16*)(ws + WS_WT3);
    u16*   wpt   = (u16*)(ws + WS_WPT);
    unsigned int* maxn = (unsigned int*)(acc + 7);

    wtrans<<<1568, 256, 0, stream>>>(W2, W3, Wp, wt2, wt3, wpt, acc);

    // ---- both branches batched (n 0..3 labeled, 4..7 unlabeled) ----
    conv1_k<<<dim3(160, 8), 256, 0, stream>>>(x_l, x_ul, W1, fea1b);
    conv3x3_nhwc<64,128,160,80,2><<<dim3(100, 1, 8), 256, 0, stream>>>(fea1b, wt2, fea2b);
    conv3x3_nhwc<128,256,80,40,2><<<dim3(25, 2, 8), 256, 0, stream>>>(fea2b, wt3, fea3b);

    cls_ul_fused<<<200, 256, 0, stream>>>(fea3b, Wc, bc, z_ema, zls, labA, acc, fc);
    loss_sup_kernel<<<512, 256, 0, stream>>>(zls, y_l, bc, acc);

    proj_mfma<<<400, 256, 0, stream>>>(fea3b, wpt, featT);
    ema_scatter<<<100, 256, 0, stream>>>(proj_ema, featT, maxn);
    class_sum<<<128, 256, 0, stream>>>(featT, labA, csum, acc);

    contrast_sE<<<dim3(NJS, 32), 256, 0, stream>>>(featT, maxn, part);
    merge_contrast<<<64, 128, 0, stream>>>(part, fc, maxn, featT, labA, csum, acc);
    final_kernel<<<1, 64, 0, stream>>>(acc, epoch, out);
}